// Round 2
// baseline (2156.018 us; speedup 1.0000x reference)
//
#include <hip/hip_runtime.h>

#define D 128
#define NP 65536
#define NV 1024

// ---------------- CSR build ----------------

__global__ __launch_bounds__(256)
void k_count(const int* __restrict__ vi, const int* __restrict__ pi,
             int* __restrict__ cp, int* __restrict__ cv, int nnz)
{
    int i = blockIdx.x * blockDim.x + threadIdx.x;
    int n = gridDim.x * blockDim.x;
    for (int e = i; e < nnz; e += n) {
        atomicAdd(&cp[pi[e]], 1);
        atomicAdd(&cv[vi[e]], 1);
    }
}

// single block, 1024 threads: exclusive scan of 65536 point counts (64/thread)
// and 1024 view counts (1/thread). Writes base[] and resets counts[] to base
// (counts buffer becomes the scatter cursor; after scatter it holds segment END).
__global__ __launch_bounds__(1024)
void k_scan(int* __restrict__ cp, int* __restrict__ bp,
            int* __restrict__ cv, int* __restrict__ bv)
{
    __shared__ int l[1024];
    int t = threadIdx.x;
    // ---- points ----
    int base = t * 64;
    int s = 0;
    for (int j = 0; j < 64; ++j) s += cp[base + j];
    l[t] = s;
    __syncthreads();
    for (int d = 1; d < 1024; d <<= 1) {
        int u = (t >= d) ? l[t - d] : 0;
        __syncthreads();
        l[t] += u;
        __syncthreads();
    }
    int run = l[t] - s;   // exclusive prefix of this thread's chunk
    for (int j = 0; j < 64; ++j) {
        int c = cp[base + j];
        bp[base + j] = run;
        cp[base + j] = run;   // cursor init
        run += c;
    }
    __syncthreads();
    // ---- views ----
    int c = cv[t];
    l[t] = c;
    __syncthreads();
    for (int d = 1; d < 1024; d <<= 1) {
        int u = (t >= d) ? l[t - d] : 0;
        __syncthreads();
        l[t] += u;
        __syncthreads();
    }
    int ex = l[t] - c;
    bv[t] = ex;
    cv[t] = ex;
}

__global__ __launch_bounds__(256)
void k_scatter(const int* __restrict__ vi, const int* __restrict__ pi,
               int* __restrict__ curp, int* __restrict__ curv,
               int* __restrict__ plist, int* __restrict__ vlist, int nnz)
{
    int i = blockIdx.x * blockDim.x + threadIdx.x;
    int n = gridDim.x * blockDim.x;
    for (int e = i; e < nnz; e += n) {
        int sp = atomicAdd(&curp[pi[e]], 1);
        plist[sp] = e;
        int sv = atomicAdd(&curv[vi[e]], 1);
        vlist[sv] = e;
    }
}

// ---------------- fused segment-mean + matvec ----------------
// W staged in LDS as float2 pairs: Wl[k*64+c] = (W[k][c], W[k][c+64])

__global__ __launch_bounds__(256)
void k_pointfeat(const float* __restrict__ values, const int* __restrict__ plist,
                 const int* __restrict__ pbase, const int* __restrict__ pend,
                 const float* __restrict__ W, const float* __restrict__ b,
                 float* __restrict__ pf)
{
    __shared__ float2 Wl[64 * D];      // 64 KB
    __shared__ float means[4][D];
    for (int i = threadIdx.x; i < 64 * D; i += 256) {
        int k = i >> 6, c = i & 63;
        Wl[i] = make_float2(W[k * D + c], W[k * D + c + 64]);
    }
    __syncthreads();
    int lane = threadIdx.x & 63, wv = threadIdx.x >> 6;
    int wave = blockIdx.x * 4 + wv, nw = gridDim.x * 4;
    float b0 = b[lane] * 0.25f, b1 = b[lane + 64] * 0.25f;
    for (int pt = wave; pt < NP; pt += nw) {   // NP/nw exact -> uniform trips
        int s = pbase[pt], e = pend[pt];
        float s0 = 0.f, s1 = 0.f;
        for (int i = s; i < e; ++i) {
            int ent = plist[i];
            const float* r = values + (size_t)ent * D;
            s0 += r[lane];
            s1 += r[lane + 64];
        }
        float inv = 0.25f / fmaxf((float)(e - s), 1.f);
        means[wv][lane] = s0 * inv;
        means[wv][lane + 64] = s1 * inv;
        __syncthreads();
        float a0 = b0, a1 = b1;
        const float4* m4 = (const float4*)means[wv];
        for (int k4 = 0; k4 < 32; ++k4) {
            float4 m = m4[k4];
            float mk[4] = {m.x, m.y, m.z, m.w};
            #pragma unroll
            for (int kk = 0; kk < 4; ++kk) {
                float2 w = Wl[(k4 * 4 + kk) * 64 + lane];
                a0 = fmaf(mk[kk], w.x, a0);
                a1 = fmaf(mk[kk], w.y, a1);
            }
        }
        pf[(size_t)pt * D + lane] = a0;
        pf[(size_t)pt * D + lane + 64] = a1;
        __syncthreads();
    }
}

__global__ __launch_bounds__(256)
void k_viewfeat(const float* __restrict__ values, const int* __restrict__ vlist,
                const int* __restrict__ vbase, const int* __restrict__ vend,
                const float* __restrict__ W, const float* __restrict__ b,
                float* __restrict__ vf, float* __restrict__ gs)
{
    __shared__ float2 Wl[64 * D];      // 64 KB
    __shared__ float red[4][D];
    __shared__ float means[D];
    for (int i = threadIdx.x; i < 64 * D; i += 256) {
        int k = i >> 6, c = i & 63;
        Wl[i] = make_float2(W[k * D + c], W[k * D + c + 64]);
    }
    int lane = threadIdx.x & 63, wv = threadIdx.x >> 6;
    int v = blockIdx.x;
    int s = vbase[v], e = vend[v];
    float s0 = 0.f, s1 = 0.f;
    for (int i = s + wv; i < e; i += 4) {
        int ent = vlist[i];
        const float* r = values + (size_t)ent * D;
        s0 += r[lane];
        s1 += r[lane + 64];
    }
    red[wv][lane] = s0;
    red[wv][lane + 64] = s1;
    __syncthreads();
    int t = threadIdx.x;
    if (t < D) {
        float tot = red[0][t] + red[1][t] + red[2][t] + red[3][t];
        atomicAdd(&gs[t], tot);                       // global sum = sum of view sums
        means[t] = tot * (0.25f / fmaxf((float)(e - s), 1.f));
    }
    __syncthreads();
    if (wv == 0) {
        float a0 = b[lane] * 0.25f, a1 = b[lane + 64] * 0.25f;
        const float4* m4 = (const float4*)means;
        for (int k4 = 0; k4 < 32; ++k4) {
            float4 m = m4[k4];
            float mk[4] = {m.x, m.y, m.z, m.w};
            #pragma unroll
            for (int kk = 0; kk < 4; ++kk) {
                float2 w = Wl[(k4 * 4 + kk) * 64 + lane];
                a0 = fmaf(mk[kk], w.x, a0);
                a1 = fmaf(mk[kk], w.y, a1);
            }
        }
        vf[v * D + lane] = a0;           // NOTE: no global features here
        vf[v * D + lane + 64] = a1;
    }
}

__global__ void k_global(const float* __restrict__ gs, const float* __restrict__ Wg,
                         const float* __restrict__ bg, float* __restrict__ gf, float inv_nnz)
{
    __shared__ float gm[D];
    int t = threadIdx.x;   // 128 threads
    gm[t] = gs[t] * inv_nnz;
    __syncthreads();
    float acc = bg[t];
    #pragma unroll 8
    for (int k = 0; k < D; ++k) acc = fmaf(gm[k], Wg[k * D + t], acc);
    gf[t] = acc * 0.25f;
}

// ---------------- projection + epilogue gathers ----------------

__global__ __launch_bounds__(256)
void k_proj(const float* __restrict__ values, const int* __restrict__ view_idx,
            const int* __restrict__ point_idx, const float* __restrict__ pf,
            const float* __restrict__ vfb, const float* __restrict__ W,
            const float* __restrict__ bp, const float* __restrict__ gf,
            float* __restrict__ out, int nnz)
{
    __shared__ float Wl[D * D];        // 64 KB, natural row-major
    __shared__ float rows[4][8 * D];   // 16 KB: per-wave 8 entry rows
    for (int i = threadIdx.x; i < D * D / 4; i += blockDim.x)
        ((float4*)Wl)[i] = ((const float4*)W)[i];
    __syncthreads();
    int lane = threadIdx.x & 63;
    int wv   = threadIdx.x >> 6;
    int wave = blockIdx.x * 4 + wv;
    int nw   = gridDim.x * 4;
    float base0 = bp[lane] * 0.25f + gf[lane];
    float base1 = bp[lane + 64] * 0.25f + gf[lane + 64];
    float* myr = rows[wv];
    int nb = nnz >> 3;                 // nnz divisible by 8
    for (int b = wave; b < nb; b += nw) {
        const float4* src = (const float4*)(values + (size_t)b * 8 * D);
        float4* dst = (float4*)myr;
        #pragma unroll
        for (int j = 0; j < 4; ++j) dst[j * 64 + lane] = src[j * 64 + lane];
        float acc0[8], acc1[8];
        #pragma unroll
        for (int e = 0; e < 8; ++e) { acc0[e] = 0.f; acc1[e] = 0.f; }
        const float4* r4 = (const float4*)myr;
        for (int k4 = 0; k4 < 32; ++k4) {
            float4 v[8];
            #pragma unroll
            for (int e = 0; e < 8; ++e) v[e] = r4[e * 32 + k4];
            #pragma unroll
            for (int kk = 0; kk < 4; ++kk) {
                float w0 = Wl[(k4 * 4 + kk) * D + lane];
                float w1 = Wl[(k4 * 4 + kk) * D + lane + 64];
                #pragma unroll
                for (int e = 0; e < 8; ++e) {
                    float ve = reinterpret_cast<const float*>(&v[e])[kk];
                    acc0[e] = fmaf(ve, w0, acc0[e]);
                    acc1[e] = fmaf(ve, w1, acc1[e]);
                }
            }
        }
        int e0 = b * 8;
        #pragma unroll
        for (int e = 0; e < 8; ++e) {
            int p  = point_idx[e0 + e];
            int vi = view_idx[e0 + e];
            float sp0 = pf[(size_t)p * D + lane], sp1 = pf[(size_t)p * D + lane + 64];
            float vv0 = vfb[vi * D + lane],       vv1 = vfb[vi * D + lane + 64];
            size_t o = (size_t)(e0 + e) * D + lane;
            out[o]      = fmaf(acc0[e], 0.25f, base0) + sp0 + vv0;
            out[o + 64] = fmaf(acc1[e], 0.25f, base1) + sp1 + vv1;
        }
    }
}

extern "C" void kernel_launch(void* const* d_in, const int* in_sizes, int n_in,
                              void* d_out, int out_size, void* d_ws, size_t ws_size,
                              hipStream_t stream)
{
    const float* values    = (const float*)d_in[0];
    const int*   view_idx  = (const int*)d_in[1];
    const int*   point_idx = (const int*)d_in[2];
    const float* W_sp   = (const float*)d_in[5];
    const float* b_sp   = (const float*)d_in[6];
    const float* W_view = (const float*)d_in[7];
    const float* b_view = (const float*)d_in[8];
    const float* W_glob = (const float*)d_in[9];
    const float* b_glob = (const float*)d_in[10];
    const float* W_proj = (const float*)d_in[11];
    const float* b_proj = (const float*)d_in[12];
    int nnz = in_sizes[1];

    // ws layout: [gs 128f | gf 128f | C_p 65536i | C_v 1024i | B_p 65536i |
    //             B_v 1024i | plist 1Mi | vlist 1Mi | pf 65536*128f | vf 1024*128f]
    char* w = (char*)d_ws;
    float* gs = (float*)w;                         w += 128 * 4;
    float* gf = (float*)w;                         w += 128 * 4;
    int* Cp   = (int*)w;                           w += (size_t)NP * 4;
    int* Cv   = (int*)w;                           w += (size_t)NV * 4;
    size_t zero_bytes = (size_t)(w - (char*)d_ws); // gs..Cv contiguous
    int* Bp   = (int*)w;                           w += (size_t)NP * 4;
    int* Bv   = (int*)w;                           w += (size_t)NV * 4;
    int* plist = (int*)w;                          w += (size_t)nnz * 4;
    int* vlist = (int*)w;                          w += (size_t)nnz * 4;
    float* pf = (float*)w;                         w += (size_t)NP * D * 4;
    float* vf = (float*)w;                         w += (size_t)NV * D * 4;

    hipMemsetAsync(d_ws, 0, zero_bytes, stream);

    hipLaunchKernelGGL(k_count, dim3(1024), dim3(256), 0, stream,
                       view_idx, point_idx, Cp, Cv, nnz);
    hipLaunchKernelGGL(k_scan, dim3(1), dim3(1024), 0, stream, Cp, Bp, Cv, Bv);
    hipLaunchKernelGGL(k_scatter, dim3(1024), dim3(256), 0, stream,
                       view_idx, point_idx, Cp, Cv, plist, vlist, nnz);
    hipLaunchKernelGGL(k_pointfeat, dim3(2048), dim3(256), 0, stream,
                       values, plist, Bp, Cp, W_sp, b_sp, pf);
    hipLaunchKernelGGL(k_viewfeat, dim3(NV), dim3(256), 0, stream,
                       values, vlist, Bv, Cv, W_view, b_view, vf, gs);
    hipLaunchKernelGGL(k_global, dim3(1), dim3(128), 0, stream,
                       gs, W_glob, b_glob, gf, 1.f / (float)nnz);
    hipLaunchKernelGGL(k_proj, dim3(2048), dim3(256), 0, stream,
                       values, view_idx, point_idx, pf, vf, W_proj, b_proj, gf,
                       (float*)d_out, nnz);
}

// Round 3
// 1262.202 us; speedup vs baseline: 1.7081x; 1.7081x over previous
//
#include <hip/hip_runtime.h>

#define D 128
#define NP 65536
#define NV 1024

typedef __attribute__((ext_vector_type(8))) short short8;
typedef __attribute__((ext_vector_type(4))) float f32x4;

__device__ __forceinline__ unsigned short f2bf(float x) {
    unsigned int u = __builtin_bit_cast(unsigned int, x);
    u += 0x7FFFu + ((u >> 16) & 1u);          // round-to-nearest-even
    return (unsigned short)(u >> 16);
}
__device__ __forceinline__ unsigned int pack2bf(float a, float b) {
    return (unsigned int)f2bf(a) | ((unsigned int)f2bf(b) << 16);
}

// ---------------- weight prep: W[k][n] f32 -> Wt[n][k] bf16 ----------------
__global__ __launch_bounds__(256)
void k_prep(const float* __restrict__ Wsp, const float* __restrict__ Wvw,
            const float* __restrict__ Wgl, const float* __restrict__ Wpr,
            unsigned short* __restrict__ o)
{
    const float* W = (blockIdx.x == 0) ? Wsp : (blockIdx.x == 1) ? Wvw
                   : (blockIdx.x == 2) ? Wgl : Wpr;
    unsigned short* Wt = o + (size_t)blockIdx.x * 16384;
    for (int c = threadIdx.x; c < 2048; c += 256) {
        int n = c >> 4, kb = (c & 15) * 8;
        unsigned int p[4];
        #pragma unroll
        for (int j = 0; j < 4; ++j)
            p[j] = pack2bf(W[(kb + 2 * j) * D + n], W[(kb + 2 * j + 1) * D + n]);
        *(short8*)(Wt + n * 128 + kb) = *(short8*)p;
    }
}

// ---------------- CSR build ----------------
__global__ __launch_bounds__(256)
void k_count(const int* __restrict__ vi, const int* __restrict__ pi,
             int* __restrict__ cp, int* __restrict__ cv, int nnz)
{
    int i = blockIdx.x * blockDim.x + threadIdx.x;
    int n = gridDim.x * blockDim.x;
    for (int e = i; e < nnz; e += n) {
        atomicAdd(&cp[pi[e]], 1);
        atomicAdd(&cv[vi[e]], 1);
    }
}

__global__ __launch_bounds__(1024)
void k_scan(int* __restrict__ cp, int* __restrict__ bp,
            int* __restrict__ cv, int* __restrict__ bv)
{
    __shared__ int l[1024];
    int t = threadIdx.x;
    int base = t * 64;
    int s = 0;
    for (int j = 0; j < 64; ++j) s += cp[base + j];
    l[t] = s;
    __syncthreads();
    for (int d = 1; d < 1024; d <<= 1) {
        int u = (t >= d) ? l[t - d] : 0;
        __syncthreads();
        l[t] += u;
        __syncthreads();
    }
    int run = l[t] - s;
    for (int j = 0; j < 64; ++j) {
        int c = cp[base + j];
        bp[base + j] = run;
        cp[base + j] = run;
        run += c;
    }
    __syncthreads();
    int c = cv[t];
    l[t] = c;
    __syncthreads();
    for (int d = 1; d < 1024; d <<= 1) {
        int u = (t >= d) ? l[t - d] : 0;
        __syncthreads();
        l[t] += u;
        __syncthreads();
    }
    int ex = l[t] - c;
    bv[t] = ex;
    cv[t] = ex;
}

__global__ __launch_bounds__(256)
void k_scatter(const int* __restrict__ vi, const int* __restrict__ pi,
               int* __restrict__ curp, int* __restrict__ curv,
               int* __restrict__ plist, int* __restrict__ vlist, int nnz)
{
    int i = blockIdx.x * blockDim.x + threadIdx.x;
    int n = gridDim.x * blockDim.x;
    for (int e = i; e < nnz; e += n) {
        int sp = atomicAdd(&curp[pi[e]], 1);
        plist[sp] = e;
        int sv = atomicAdd(&curv[vi[e]], 1);
        vlist[sv] = e;
    }
}

// ---------------- segment means (pure gather, no LDS) ----------------
// lane owns dims (2*lane, 2*lane+1); means written as packed bf16 rows.
__global__ __launch_bounds__(256)
void k_psum(const float* __restrict__ values, const int* __restrict__ plist,
            const int* __restrict__ pbase, const int* __restrict__ pend,
            unsigned int* __restrict__ mbuf)
{
    int lane = threadIdx.x & 63, wv = threadIdx.x >> 6;
    int wave = blockIdx.x * 4 + wv, nw = gridDim.x * 4;
    for (int pt = wave; pt < NP; pt += nw) {
        int s = pbase[pt], e = pend[pt];
        float s0 = 0.f, s1 = 0.f;
        for (int b = s; b < e; b += 64) {
            int n = min(64, e - b);
            int idx = (lane < n) ? plist[b + lane] : 0;
            for (int j = 0; j < n; ++j) {
                int ent = __builtin_amdgcn_readlane(idx, j);
                float2 v = *(const float2*)(values + (size_t)ent * D + lane * 2);
                s0 += v.x; s1 += v.y;
            }
        }
        float inv = 1.f / fmaxf((float)(e - s), 1.f);
        mbuf[(size_t)pt * 64 + lane] = pack2bf(s0 * inv, s1 * inv);
    }
}

__global__ __launch_bounds__(256)
void k_vsum(const float* __restrict__ values, const int* __restrict__ vlist,
            const int* __restrict__ vbase, const int* __restrict__ vend,
            unsigned int* __restrict__ mbuf, float* __restrict__ gs)
{
    __shared__ float2 red[4][64];
    int lane = threadIdx.x & 63, wv = threadIdx.x >> 6;
    int v = blockIdx.x;
    int s = vbase[v], e = vend[v];
    float s0 = 0.f, s1 = 0.f;
    for (int b = s + wv * 64; b < e; b += 256) {
        int n = min(64, e - b);
        int idx = (lane < n) ? vlist[b + lane] : 0;
        for (int j = 0; j < n; ++j) {
            int ent = __builtin_amdgcn_readlane(idx, j);
            float2 vv = *(const float2*)(values + (size_t)ent * D + lane * 2);
            s0 += vv.x; s1 += vv.y;
        }
    }
    red[wv][lane] = make_float2(s0, s1);
    __syncthreads();
    if (wv == 0) {
        float2 a = red[0][lane], b2 = red[1][lane], c = red[2][lane], d2 = red[3][lane];
        float t0 = a.x + b2.x + c.x + d2.x;
        float t1 = a.y + b2.y + c.y + d2.y;
        atomicAdd(&gs[lane * 2], t0);
        atomicAdd(&gs[lane * 2 + 1], t1);
        float inv = 1.f / fmaxf((float)(e - s), 1.f);
        mbuf[(size_t)(NP + v) * 64 + lane] = pack2bf(t0 * inv, t1 * inv);
    }
}

// ---------------- shared MFMA tile machinery ----------------
// LDS layout: bf16 [128 rows][128 k], byte addr = (row*256 + k*2) ^ ((row&7)<<4)

__device__ __forceinline__ void stage_bf16(const unsigned short* __restrict__ g,
                                           unsigned short* lds, int t)
{
    #pragma unroll
    for (int i = 0; i < 8; ++i) {
        int c = i * 256 + t;
        int row = c >> 4, kb = (c & 15) * 16;
        short8 v = *(const short8*)(g + row * 128 + (c & 15) * 8);
        *(short8*)&lds[((row * 256 + kb) ^ ((row & 7) << 4)) >> 1] = v;
    }
}

__device__ __forceinline__ void stage_f32_cvt(const float* __restrict__ g, int validrows,
                                              unsigned short* lds, int t)
{
    #pragma unroll
    for (int i = 0; i < 8; ++i) {
        int c = i * 256 + t;
        int row = c >> 4, cb = (c & 15) * 8;
        unsigned int p[4] = {0u, 0u, 0u, 0u};
        if (row < validrows) {
            const float4* src = (const float4*)(g + (size_t)row * D + cb);
            float4 u = src[0], v = src[1];
            p[0] = pack2bf(u.x, u.y); p[1] = pack2bf(u.z, u.w);
            p[2] = pack2bf(v.x, v.y); p[3] = pack2bf(v.z, v.w);
        }
        *(short8*)&lds[((row * 256 + cb * 2) ^ ((row & 7) << 4)) >> 1] = *(short8*)p;
    }
}

__device__ __forceinline__ void mfma_tile(const unsigned short* Al, const unsigned short* Bl,
                                          int lane, int w, f32x4 acc[8][2])
{
    int lr = lane & 15, lg = lane >> 4;
    #pragma unroll
    for (int kc = 0; kc < 4; ++kc) {
        int kb = kc * 64 + lg * 16;   // byte offset of this frag's k-slice
        int bn0 = w * 32 + lr, bn1 = bn0 + 16;
        short8 b0 = *(const short8*)&Bl[((bn0 * 256 + kb) ^ ((bn0 & 7) << 4)) >> 1];
        short8 b1 = *(const short8*)&Bl[((bn1 * 256 + kb) ^ ((bn1 & 7) << 4)) >> 1];
        #pragma unroll
        for (int m = 0; m < 8; ++m) {
            int row = m * 16 + lr;
            short8 a = *(const short8*)&Al[((row * 256 + kb) ^ ((row & 7) << 4)) >> 1];
            acc[m][0] = __builtin_amdgcn_mfma_f32_16x16x32_bf16(a, b0, acc[m][0], 0, 0, 0);
            acc[m][1] = __builtin_amdgcn_mfma_f32_16x16x32_bf16(a, b1, acc[m][1], 0, 0, 0);
        }
    }
}

// ---------------- feature GEMM over all mean rows ----------------
__global__ __launch_bounds__(256)
void k_featgemm(const unsigned int* __restrict__ mbuf, const unsigned short* __restrict__ Wt4,
                const float* __restrict__ bSp, const float* __restrict__ bVw,
                const float* __restrict__ bGl, const float* __restrict__ gs,
                float inv_nnz, float* __restrict__ fbuf)
{
    __shared__ unsigned short Al[128 * 128];
    __shared__ unsigned short Bl[128 * 128];
    int t = threadIdx.x;
    int tile = blockIdx.x;   // 0..520
    const unsigned short* Wt; const float* bias; int rowbase; int vrows = 128;
    if (tile < 512)      { Wt = Wt4;             bias = bSp; rowbase = tile * 128; }
    else if (tile < 520) { Wt = Wt4 + 16384;     bias = bVw; rowbase = NP + (tile - 512) * 128; }
    else                 { Wt = Wt4 + 2 * 16384; bias = bGl; rowbase = NP + NV; vrows = 1; }
    stage_bf16(Wt, Bl, t);
    if (tile < 520) {
        stage_bf16((const unsigned short*)(mbuf + (size_t)rowbase * 64), Al, t);
    } else {
        #pragma unroll
        for (int i = 0; i < 8; ++i) {
            int c = i * 256 + t;
            int row = c >> 4, cb = (c & 15) * 8;
            unsigned int p[4] = {0u, 0u, 0u, 0u};
            if (row == 0) {
                #pragma unroll
                for (int j = 0; j < 4; ++j)
                    p[j] = pack2bf(gs[cb + 2 * j] * inv_nnz, gs[cb + 2 * j + 1] * inv_nnz);
            }
            *(short8*)&Al[((row * 256 + cb * 2) ^ ((row & 7) << 4)) >> 1] = *(short8*)p;
        }
    }
    __syncthreads();
    f32x4 acc[8][2] = {};
    int lane = t & 63, w = t >> 6;
    mfma_tile(Al, Bl, lane, w, acc);
    int lr = lane & 15, lg = lane >> 4;
    int c0 = w * 32 + lr, c1 = c0 + 16;
    float bb0 = 0.25f * bias[c0], bb1 = 0.25f * bias[c1];
    #pragma unroll
    for (int m = 0; m < 8; ++m)
        #pragma unroll
        for (int r = 0; r < 4; ++r) {
            int row = m * 16 + lg * 4 + r;
            if (row < vrows) {
                fbuf[(size_t)(rowbase + row) * D + c0] = acc[m][0][r] * 0.25f + bb0;
                fbuf[(size_t)(rowbase + row) * D + c1] = acc[m][1][r] * 0.25f + bb1;
            }
        }
}

// ---------------- projection + epilogue ----------------
__global__ __launch_bounds__(256)
void k_proj(const float* __restrict__ values, const int* __restrict__ view_idx,
            const int* __restrict__ point_idx, const unsigned short* __restrict__ WtPr,
            const float* __restrict__ bPr, const float* __restrict__ fbuf,
            float* __restrict__ out, int nnz)
{
    __shared__ unsigned short Al[128 * 128];
    __shared__ unsigned short Bl[128 * 128];
    __shared__ int pI[128], vI[128];
    int t = threadIdx.x;
    int e0 = blockIdx.x * 128;
    int vrows = min(128, nnz - e0);
    stage_bf16(WtPr, Bl, t);
    stage_f32_cvt(values + (size_t)e0 * D, vrows, Al, t);
    if (t < 128) pI[t] = (t < vrows) ? point_idx[e0 + t] : 0;
    else { int u = t - 128; vI[u] = (u < vrows) ? view_idx[e0 + u] : 0; }
    __syncthreads();
    f32x4 acc[8][2] = {};
    int lane = t & 63, w = t >> 6;
    mfma_tile(Al, Bl, lane, w, acc);
    int lr = lane & 15, lg = lane >> 4;
    int c0 = w * 32 + lr, c1 = c0 + 16;
    const float* gfr = fbuf + (size_t)(NP + NV) * D;
    float base0 = 0.25f * bPr[c0] + gfr[c0];
    float base1 = 0.25f * bPr[c1] + gfr[c1];
    const float* pf = fbuf;
    const float* vf = fbuf + (size_t)NP * D;
    #pragma unroll
    for (int m = 0; m < 8; ++m)
        #pragma unroll
        for (int r = 0; r < 4; ++r) {
            int row = m * 16 + lg * 4 + r;
            if (row < vrows) {
                int p = pI[row], vv = vI[row];
                size_t o = (size_t)(e0 + row) * D;
                out[o + c0] = acc[m][0][r] * 0.25f + base0 + pf[(size_t)p * D + c0] + vf[(size_t)vv * D + c0];
                out[o + c1] = acc[m][1][r] * 0.25f + base1 + pf[(size_t)p * D + c1] + vf[(size_t)vv * D + c1];
            }
        }
}

extern "C" void kernel_launch(void* const* d_in, const int* in_sizes, int n_in,
                              void* d_out, int out_size, void* d_ws, size_t ws_size,
                              hipStream_t stream)
{
    const float* values    = (const float*)d_in[0];
    const int*   view_idx  = (const int*)d_in[1];
    const int*   point_idx = (const int*)d_in[2];
    const float* W_sp   = (const float*)d_in[5];
    const float* b_sp   = (const float*)d_in[6];
    const float* W_view = (const float*)d_in[7];
    const float* b_view = (const float*)d_in[8];
    const float* W_glob = (const float*)d_in[9];
    const float* b_glob = (const float*)d_in[10];
    const float* W_proj = (const float*)d_in[11];
    const float* b_proj = (const float*)d_in[12];
    int nnz = in_sizes[1];

    // ws: [gs 128f | Cp | Cv] (memset) | Bp | Bv | plist | vlist | Wt4 | mbuf | fbuf
    char* w = (char*)d_ws;
    float* gs = (float*)w;                          w += 128 * 4;
    int* Cp   = (int*)w;                            w += (size_t)NP * 4;
    int* Cv   = (int*)w;                            w += (size_t)NV * 4;
    size_t zero_bytes = (size_t)(w - (char*)d_ws);
    int* Bp   = (int*)w;                            w += (size_t)NP * 4;
    int* Bv   = (int*)w;                            w += (size_t)NV * 4;
    int* plist = (int*)w;                           w += (size_t)nnz * 4;
    int* vlist = (int*)w;                           w += (size_t)nnz * 4;
    unsigned short* Wt4 = (unsigned short*)w;       w += (size_t)4 * 16384 * 2;
    unsigned int* mbuf = (unsigned int*)w;          w += (size_t)(NP + NV) * 64 * 4;
    float* fbuf = (float*)w;                        w += (size_t)(NP + NV + 1) * D * 4;

    hipMemsetAsync(d_ws, 0, zero_bytes, stream);

    hipLaunchKernelGGL(k_prep, dim3(4), dim3(256), 0, stream,
                       W_sp, W_view, W_glob, W_proj, Wt4);
    hipLaunchKernelGGL(k_count, dim3(1024), dim3(256), 0, stream,
                       view_idx, point_idx, Cp, Cv, nnz);
    hipLaunchKernelGGL(k_scan, dim3(1), dim3(1024), 0, stream, Cp, Bp, Cv, Bv);
    hipLaunchKernelGGL(k_scatter, dim3(1024), dim3(256), 0, stream,
                       view_idx, point_idx, Cp, Cv, plist, vlist, nnz);
    hipLaunchKernelGGL(k_psum, dim3(2048), dim3(256), 0, stream,
                       values, plist, Bp, Cp, mbuf);
    hipLaunchKernelGGL(k_vsum, dim3(NV), dim3(256), 0, stream,
                       values, vlist, Bv, Cv, mbuf, gs);
    hipLaunchKernelGGL(k_featgemm, dim3(521), dim3(256), 0, stream,
                       mbuf, Wt4, b_sp, b_view, b_glob, gs, 1.f / (float)nnz, fbuf);
    hipLaunchKernelGGL(k_proj, dim3((nnz + 127) / 128), dim3(256), 0, stream,
                       values, view_idx, point_idx, Wt4 + (size_t)3 * 16384, b_proj, fbuf,
                       (float*)d_out, nnz);
}

// Round 4
// 1174.619 us; speedup vs baseline: 1.8355x; 1.0746x over previous
//
#include <hip/hip_runtime.h>

#define D 128
#define NP 65536
#define NV 1024

typedef __attribute__((ext_vector_type(8))) short short8;
typedef __attribute__((ext_vector_type(4))) float f32x4;

__device__ __forceinline__ unsigned short f2bf(float x) {
    unsigned int u = __builtin_bit_cast(unsigned int, x);
    u += 0x7FFFu + ((u >> 16) & 1u);          // round-to-nearest-even
    return (unsigned short)(u >> 16);
}
__device__ __forceinline__ unsigned int pack2bf(float a, float b) {
    return (unsigned int)f2bf(a) | ((unsigned int)f2bf(b) << 16);
}

// ---------------- weight prep: W[k][n] f32 -> Wt[n][k] bf16 ----------------
__global__ __launch_bounds__(256)
void k_prep(const float* __restrict__ Wsp, const float* __restrict__ Wvw,
            const float* __restrict__ Wgl, const float* __restrict__ Wpr,
            unsigned short* __restrict__ o)
{
    const float* W = (blockIdx.x == 0) ? Wsp : (blockIdx.x == 1) ? Wvw
                   : (blockIdx.x == 2) ? Wgl : Wpr;
    unsigned short* Wt = o + (size_t)blockIdx.x * 16384;
    for (int c = threadIdx.x; c < 2048; c += 256) {
        int n = c >> 4, kb = (c & 15) * 8;
        unsigned int p[4];
        #pragma unroll
        for (int j = 0; j < 4; ++j)
            p[j] = pack2bf(W[(kb + 2 * j) * D + n], W[(kb + 2 * j + 1) * D + n]);
        *(short8*)(Wt + n * 128 + kb) = *(short8*)p;
    }
}

// ---------------- CSR build ----------------
__global__ __launch_bounds__(256)
void k_count(const int* __restrict__ vi, const int* __restrict__ pi,
             int* __restrict__ cp, int* __restrict__ cv, int nnz)
{
    int i = blockIdx.x * blockDim.x + threadIdx.x;
    int n = gridDim.x * blockDim.x;
    for (int e = i; e < nnz; e += n) {
        atomicAdd(&cp[pi[e]], 1);
        atomicAdd(&cv[vi[e]], 1);
    }
}

// hierarchical scan: A) 64 blocks reduce 1024 counts each
__global__ __launch_bounds__(256)
void k_scanA(const int* __restrict__ cp, int* __restrict__ bsum)
{
    __shared__ int l[256];
    int t = threadIdx.x;
    int4 c = ((const int4*)cp)[blockIdx.x * 256 + t];
    l[t] = c.x + c.y + c.z + c.w;
    __syncthreads();
    for (int d = 128; d > 0; d >>= 1) {
        if (t < d) l[t] += l[t + d];
        __syncthreads();
    }
    if (t == 0) bsum[blockIdx.x] = l[0];
}

// B) scan the 64 block sums + full view scan (1024)
__global__ __launch_bounds__(256)
void k_scanB(const int* __restrict__ bsum, int* __restrict__ bbase,
             int* __restrict__ cv, int* __restrict__ bv)
{
    __shared__ int l[256];
    int t = threadIdx.x;
    int own = (t < 64) ? bsum[t] : 0;
    l[t] = own;
    __syncthreads();
    for (int d = 1; d < 64; d <<= 1) {
        int u = (t >= d && t < 64) ? l[t - d] : 0;
        __syncthreads();
        if (t < 64) l[t] += u;
        __syncthreads();
    }
    if (t < 64) bbase[t] = l[t] - own;
    __syncthreads();
    // views: 1024 ints, int4 per thread
    int4 c = ((const int4*)cv)[t];
    int s4 = c.x + c.y + c.z + c.w;
    l[t] = s4;
    __syncthreads();
    for (int d = 1; d < 256; d <<= 1) {
        int u = (t >= d) ? l[t - d] : 0;
        __syncthreads();
        l[t] += u;
        __syncthreads();
    }
    int ex = l[t] - s4;
    int4 o; o.x = ex; o.y = ex + c.x; o.z = o.y + c.y; o.w = o.z + c.z;
    ((int4*)bv)[t] = o;
    ((int4*)cv)[t] = o;
}

// C) 64 blocks: local exclusive scan + block base -> Bp and cursor Cp
__global__ __launch_bounds__(256)
void k_scanC(int* __restrict__ cp, int* __restrict__ bp, const int* __restrict__ bbase)
{
    __shared__ int l[256];
    int t = threadIdx.x;
    int i = blockIdx.x * 256 + t;
    int4 c = ((const int4*)cp)[i];
    int s4 = c.x + c.y + c.z + c.w;
    l[t] = s4;
    __syncthreads();
    for (int d = 1; d < 256; d <<= 1) {
        int u = (t >= d) ? l[t - d] : 0;
        __syncthreads();
        l[t] += u;
        __syncthreads();
    }
    int ex = l[t] - s4 + bbase[blockIdx.x];
    int4 o; o.x = ex; o.y = ex + c.x; o.z = o.y + c.y; o.w = o.z + c.z;
    ((int4*)bp)[i] = o;
    ((int4*)cp)[i] = o;
}

__global__ __launch_bounds__(256)
void k_scatter(const int* __restrict__ vi, const int* __restrict__ pi,
               int* __restrict__ curp, int* __restrict__ curv,
               int* __restrict__ plist, int* __restrict__ vlist, int nnz)
{
    int i = blockIdx.x * blockDim.x + threadIdx.x;
    int n = gridDim.x * blockDim.x;
    for (int e = i; e < nnz; e += n) {
        int sp = atomicAdd(&curp[pi[e]], 1);
        plist[sp] = e;
        int sv = atomicAdd(&curv[vi[e]], 1);
        vlist[sv] = e;
    }
}

// ---------------- segment means (gather, 4 rows in flight) ----------------
__global__ __launch_bounds__(256)
void k_psum(const float* __restrict__ values, const int* __restrict__ plist,
            const int* __restrict__ pbase, const int* __restrict__ pend,
            unsigned int* __restrict__ mbuf)
{
    int lane = threadIdx.x & 63, wv = threadIdx.x >> 6;
    int wave = blockIdx.x * 4 + wv, nw = gridDim.x * 4;
    for (int pt = wave; pt < NP; pt += nw) {
        int s = pbase[pt], e = pend[pt];
        float s0 = 0.f, s1 = 0.f;
        for (int b = s; b < e; b += 64) {
            int n = min(64, e - b);
            int idx = (lane < n) ? plist[b + lane] : 0;
            int j = 0;
            for (; j + 4 <= n; j += 4) {
                int e0 = __builtin_amdgcn_readlane(idx, j);
                int e1 = __builtin_amdgcn_readlane(idx, j + 1);
                int e2 = __builtin_amdgcn_readlane(idx, j + 2);
                int e3 = __builtin_amdgcn_readlane(idx, j + 3);
                float2 a = *(const float2*)(values + (size_t)e0 * D + lane * 2);
                float2 b2 = *(const float2*)(values + (size_t)e1 * D + lane * 2);
                float2 c = *(const float2*)(values + (size_t)e2 * D + lane * 2);
                float2 d = *(const float2*)(values + (size_t)e3 * D + lane * 2);
                s0 += a.x + b2.x + c.x + d.x;
                s1 += a.y + b2.y + c.y + d.y;
            }
            for (; j < n; ++j) {
                int ent = __builtin_amdgcn_readlane(idx, j);
                float2 v = *(const float2*)(values + (size_t)ent * D + lane * 2);
                s0 += v.x; s1 += v.y;
            }
        }
        float inv = 1.f / fmaxf((float)(e - s), 1.f);
        mbuf[(size_t)pt * 64 + lane] = pack2bf(s0 * inv, s1 * inv);
    }
}

__global__ __launch_bounds__(256)
void k_vsum(const float* __restrict__ values, const int* __restrict__ vlist,
            const int* __restrict__ vbase, const int* __restrict__ vend,
            unsigned int* __restrict__ mbuf, float* __restrict__ gs)
{
    __shared__ float2 red[4][64];
    int lane = threadIdx.x & 63, wv = threadIdx.x >> 6;
    int v = blockIdx.x;
    int s = vbase[v], e = vend[v];
    float s0 = 0.f, s1 = 0.f;
    for (int b = s + wv * 64; b < e; b += 256) {
        int n = min(64, e - b);
        int idx = (lane < n) ? vlist[b + lane] : 0;
        int j = 0;
        for (; j + 4 <= n; j += 4) {
            int e0 = __builtin_amdgcn_readlane(idx, j);
            int e1 = __builtin_amdgcn_readlane(idx, j + 1);
            int e2 = __builtin_amdgcn_readlane(idx, j + 2);
            int e3 = __builtin_amdgcn_readlane(idx, j + 3);
            float2 a = *(const float2*)(values + (size_t)e0 * D + lane * 2);
            float2 b2 = *(const float2*)(values + (size_t)e1 * D + lane * 2);
            float2 c = *(const float2*)(values + (size_t)e2 * D + lane * 2);
            float2 d = *(const float2*)(values + (size_t)e3 * D + lane * 2);
            s0 += a.x + b2.x + c.x + d.x;
            s1 += a.y + b2.y + c.y + d.y;
        }
        for (; j < n; ++j) {
            int ent = __builtin_amdgcn_readlane(idx, j);
            float2 vv = *(const float2*)(values + (size_t)ent * D + lane * 2);
            s0 += vv.x; s1 += vv.y;
        }
    }
    red[wv][lane] = make_float2(s0, s1);
    __syncthreads();
    if (wv == 0) {
        float2 a = red[0][lane], b2 = red[1][lane], c = red[2][lane], d2 = red[3][lane];
        float t0 = a.x + b2.x + c.x + d2.x;
        float t1 = a.y + b2.y + c.y + d2.y;
        atomicAdd(&gs[lane * 2], t0);
        atomicAdd(&gs[lane * 2 + 1], t1);
        float inv = 1.f / fmaxf((float)(e - s), 1.f);
        mbuf[(size_t)(NP + v) * 64 + lane] = pack2bf(t0 * inv, t1 * inv);
    }
}

// ---------------- shared MFMA tile machinery ----------------
// LDS layout: bf16 [128 rows][128 k], byte addr = (row*256 + k*2) ^ ((row&7)<<4)

__device__ __forceinline__ void stage_bf16(const unsigned short* __restrict__ g,
                                           unsigned short* lds, int t)
{
    #pragma unroll
    for (int i = 0; i < 8; ++i) {
        int c = i * 256 + t;
        int row = c >> 4, kb = (c & 15) * 16;
        short8 v = *(const short8*)(g + row * 128 + (c & 15) * 8);
        *(short8*)&lds[((row * 256 + kb) ^ ((row & 7) << 4)) >> 1] = v;
    }
}

__device__ __forceinline__ void stage_f32_cvt(const float* __restrict__ g, int validrows,
                                              unsigned short* lds, int t)
{
    #pragma unroll 4
    for (int i = 0; i < 8; ++i) {
        int c = i * 256 + t;
        int row = c >> 4, cb = (c & 15) * 8;
        unsigned int p[4] = {0u, 0u, 0u, 0u};
        if (row < validrows) {
            const float4* src = (const float4*)(g + (size_t)row * D + cb);
            float4 u = src[0], v = src[1];
            p[0] = pack2bf(u.x, u.y); p[1] = pack2bf(u.z, u.w);
            p[2] = pack2bf(v.x, v.y); p[3] = pack2bf(v.z, v.w);
        }
        *(short8*)&lds[((row * 256 + cb * 2) ^ ((row & 7) << 4)) >> 1] = *(short8*)p;
    }
}

__device__ __forceinline__ void mfma_tile(const unsigned short* Al, const unsigned short* Bl,
                                          int lane, int w, f32x4 acc[8][2])
{
    int lr = lane & 15, lg = lane >> 4;
    #pragma unroll
    for (int kc = 0; kc < 4; ++kc) {
        int kb = kc * 64 + lg * 16;
        int bn0 = w * 32 + lr, bn1 = bn0 + 16;
        short8 b0 = *(const short8*)&Bl[((bn0 * 256 + kb) ^ ((bn0 & 7) << 4)) >> 1];
        short8 b1 = *(const short8*)&Bl[((bn1 * 256 + kb) ^ ((bn1 & 7) << 4)) >> 1];
        #pragma unroll
        for (int m = 0; m < 8; ++m) {
            int row = m * 16 + lr;
            short8 a = *(const short8*)&Al[((row * 256 + kb) ^ ((row & 7) << 4)) >> 1];
            acc[m][0] = __builtin_amdgcn_mfma_f32_16x16x32_bf16(a, b0, acc[m][0], 0, 0, 0);
            acc[m][1] = __builtin_amdgcn_mfma_f32_16x16x32_bf16(a, b1, acc[m][1], 0, 0, 0);
        }
    }
}

// ---------------- feature GEMM over all mean rows ----------------
__global__ __launch_bounds__(256)
void k_featgemm(const unsigned int* __restrict__ mbuf, const unsigned short* __restrict__ Wt4,
                const float* __restrict__ bSp, const float* __restrict__ bVw,
                const float* __restrict__ bGl, const float* __restrict__ gs,
                float inv_nnz, float* __restrict__ fbuf)
{
    __shared__ unsigned short Al[128 * 128];
    __shared__ unsigned short Bl[128 * 128];
    int t = threadIdx.x;
    int tile = blockIdx.x;   // 0..520
    const unsigned short* Wt; const float* bias; int rowbase; int vrows = 128;
    if (tile < 512)      { Wt = Wt4;             bias = bSp; rowbase = tile * 128; }
    else if (tile < 520) { Wt = Wt4 + 16384;     bias = bVw; rowbase = NP + (tile - 512) * 128; }
    else                 { Wt = Wt4 + 2 * 16384; bias = bGl; rowbase = NP + NV; vrows = 1; }
    stage_bf16(Wt, Bl, t);
    if (tile < 520) {
        stage_bf16((const unsigned short*)(mbuf + (size_t)rowbase * 64), Al, t);
    } else {
        #pragma unroll
        for (int i = 0; i < 8; ++i) {
            int c = i * 256 + t;
            int row = c >> 4, cb = (c & 15) * 8;
            unsigned int p[4] = {0u, 0u, 0u, 0u};
            if (row == 0) {
                #pragma unroll
                for (int j = 0; j < 4; ++j)
                    p[j] = pack2bf(gs[cb + 2 * j] * inv_nnz, gs[cb + 2 * j + 1] * inv_nnz);
            }
            *(short8*)&Al[((row * 256 + cb * 2) ^ ((row & 7) << 4)) >> 1] = *(short8*)p;
        }
    }
    __syncthreads();
    f32x4 acc[8][2] = {};
    int lane = t & 63, w = t >> 6;
    mfma_tile(Al, Bl, lane, w, acc);
    int lr = lane & 15, lg = lane >> 4;
    int c0 = w * 32 + lr, c1 = c0 + 16;
    float bb0 = 0.25f * bias[c0], bb1 = 0.25f * bias[c1];
    #pragma unroll
    for (int m = 0; m < 8; ++m)
        #pragma unroll
        for (int r = 0; r < 4; ++r) {
            int row = m * 16 + lg * 4 + r;
            if (row < vrows) {
                fbuf[(size_t)(rowbase + row) * D + c0] = acc[m][0][r] * 0.25f + bb0;
                fbuf[(size_t)(rowbase + row) * D + c1] = acc[m][1][r] * 0.25f + bb1;
            }
        }
}

// ---------------- projection: B in registers, A in LDS, grid-stride ----------------
__global__ __launch_bounds__(256, 4)
void k_proj(const float* __restrict__ values, const int* __restrict__ view_idx,
            const int* __restrict__ point_idx, const unsigned short* __restrict__ WtPr,
            const float* __restrict__ bPr, const float* __restrict__ fbuf,
            float* __restrict__ out, int nnz, int ntiles)
{
    __shared__ unsigned short Al[128 * 128];   // 32 KB
    __shared__ int pI[128], vI[128];
    int t = threadIdx.x, lane = t & 63, w = t >> 6;
    int lr = lane & 15, lg = lane >> 4;
    // persistent B fragments: col = w*32+lr (+16), k-slice lg*8, per kc
    short8 Bf[4][2];
    #pragma unroll
    for (int kc = 0; kc < 4; ++kc) {
        Bf[kc][0] = *(const short8*)(WtPr + (w * 32 + lr) * 128 + kc * 32 + lg * 8);
        Bf[kc][1] = *(const short8*)(WtPr + (w * 32 + lr + 16) * 128 + kc * 32 + lg * 8);
    }
    int c0 = w * 32 + lr, c1 = c0 + 16;
    const float* gfr = fbuf + (size_t)(NP + NV) * D;
    float base0 = 0.25f * bPr[c0] + gfr[c0];
    float base1 = 0.25f * bPr[c1] + gfr[c1];
    const float* pf = fbuf;
    const float* vf = fbuf + (size_t)NP * D;
    for (int tile = blockIdx.x; tile < ntiles; tile += gridDim.x) {
        int e0 = tile * 128;
        int vrows = min(128, nnz - e0);
        stage_f32_cvt(values + (size_t)e0 * D, vrows, Al, t);
        if (t < 128) pI[t] = (t < vrows) ? point_idx[e0 + t] : 0;
        else { int u = t - 128; vI[u] = (u < vrows) ? view_idx[e0 + u] : 0; }
        __syncthreads();
        f32x4 acc[8][2] = {};
        #pragma unroll
        for (int kc = 0; kc < 4; ++kc) {
            int kb = kc * 64 + lg * 16;
            #pragma unroll
            for (int m = 0; m < 8; ++m) {
                int row = m * 16 + lr;
                short8 a = *(const short8*)&Al[((row * 256 + kb) ^ ((row & 7) << 4)) >> 1];
                acc[m][0] = __builtin_amdgcn_mfma_f32_16x16x32_bf16(a, Bf[kc][0], acc[m][0], 0, 0, 0);
                acc[m][1] = __builtin_amdgcn_mfma_f32_16x16x32_bf16(a, Bf[kc][1], acc[m][1], 0, 0, 0);
            }
        }
        #pragma unroll
        for (int m = 0; m < 8; ++m)
            #pragma unroll
            for (int r = 0; r < 4; ++r) {
                int row = m * 16 + lg * 4 + r;
                if (row < vrows) {
                    int p = pI[row], vv = vI[row];
                    size_t o = (size_t)(e0 + row) * D;
                    out[o + c0] = acc[m][0][r] * 0.25f + base0 + pf[(size_t)p * D + c0] + vf[(size_t)vv * D + c0];
                    out[o + c1] = acc[m][1][r] * 0.25f + base1 + pf[(size_t)p * D + c1] + vf[(size_t)vv * D + c1];
                }
            }
        __syncthreads();   // protect Al/pI/vI before next tile
    }
}

extern "C" void kernel_launch(void* const* d_in, const int* in_sizes, int n_in,
                              void* d_out, int out_size, void* d_ws, size_t ws_size,
                              hipStream_t stream)
{
    const float* values    = (const float*)d_in[0];
    const int*   view_idx  = (const int*)d_in[1];
    const int*   point_idx = (const int*)d_in[2];
    const float* W_sp   = (const float*)d_in[5];
    const float* b_sp   = (const float*)d_in[6];
    const float* W_view = (const float*)d_in[7];
    const float* b_view = (const float*)d_in[8];
    const float* W_glob = (const float*)d_in[9];
    const float* b_glob = (const float*)d_in[10];
    const float* W_proj = (const float*)d_in[11];
    const float* b_proj = (const float*)d_in[12];
    int nnz = in_sizes[1];

    // ws: [gs | Cp | Cv] (memset) | bsum | bbase | Bp | Bv | plist | vlist | Wt4 | mbuf | fbuf
    char* w = (char*)d_ws;
    float* gs = (float*)w;                          w += 128 * 4;
    int* Cp   = (int*)w;                            w += (size_t)NP * 4;
    int* Cv   = (int*)w;                            w += (size_t)NV * 4;
    size_t zero_bytes = (size_t)(w - (char*)d_ws);
    int* bsum = (int*)w;                            w += 64 * 4;
    int* bbase = (int*)w;                           w += 64 * 4;
    int* Bp   = (int*)w;                            w += (size_t)NP * 4;
    int* Bv   = (int*)w;                            w += (size_t)NV * 4;
    int* plist = (int*)w;                           w += (size_t)nnz * 4;
    int* vlist = (int*)w;                           w += (size_t)nnz * 4;
    unsigned short* Wt4 = (unsigned short*)w;       w += (size_t)4 * 16384 * 2;
    unsigned int* mbuf = (unsigned int*)w;          w += (size_t)(NP + NV) * 64 * 4;
    float* fbuf = (float*)w;                        w += (size_t)(NP + NV + 1) * D * 4;

    hipMemsetAsync(d_ws, 0, zero_bytes, stream);

    hipLaunchKernelGGL(k_prep, dim3(4), dim3(256), 0, stream,
                       W_sp, W_view, W_glob, W_proj, Wt4);
    hipLaunchKernelGGL(k_count, dim3(1024), dim3(256), 0, stream,
                       view_idx, point_idx, Cp, Cv, nnz);
    hipLaunchKernelGGL(k_scanA, dim3(64), dim3(256), 0, stream, Cp, bsum);
    hipLaunchKernelGGL(k_scanB, dim3(1), dim3(256), 0, stream, bsum, bbase, Cv, Bv);
    hipLaunchKernelGGL(k_scanC, dim3(64), dim3(256), 0, stream, Cp, Bp, bbase);
    hipLaunchKernelGGL(k_scatter, dim3(1024), dim3(256), 0, stream,
                       view_idx, point_idx, Cp, Cv, plist, vlist, nnz);
    hipLaunchKernelGGL(k_psum, dim3(2048), dim3(256), 0, stream,
                       values, plist, Bp, Cp, mbuf);
    hipLaunchKernelGGL(k_vsum, dim3(NV), dim3(256), 0, stream,
                       values, vlist, Bv, Cv, mbuf, gs);
    hipLaunchKernelGGL(k_featgemm, dim3(521), dim3(256), 0, stream,
                       mbuf, Wt4, b_sp, b_view, b_glob, gs, 1.f / (float)nnz, fbuf);
    int ntiles = (nnz + 127) / 128;
    hipLaunchKernelGGL(k_proj, dim3(2048), dim3(256), 0, stream,
                       values, view_idx, point_idx, Wt4 + (size_t)3 * 16384, b_proj, fbuf,
                       (float*)d_out, nnz, ntiles);
}

// Round 5
// 1136.891 us; speedup vs baseline: 1.8964x; 1.0332x over previous
//
#include <hip/hip_runtime.h>

#define D 128
#define NP 65536
#define NV 1024

typedef __attribute__((ext_vector_type(8))) short short8;
typedef __attribute__((ext_vector_type(4))) float f32x4;

__device__ __forceinline__ unsigned short f2bf(float x) {
    unsigned int u = __builtin_bit_cast(unsigned int, x);
    u += 0x7FFFu + ((u >> 16) & 1u);          // round-to-nearest-even
    return (unsigned short)(u >> 16);
}
__device__ __forceinline__ unsigned int pack2bf(float a, float b) {
    return (unsigned int)f2bf(a) | ((unsigned int)f2bf(b) << 16);
}
__device__ __forceinline__ float bf2f(unsigned short u) {
    return __builtin_bit_cast(float, ((unsigned int)u) << 16);
}
__device__ __forceinline__ float bflo(unsigned int u) {
    return __builtin_bit_cast(float, u << 16);
}
__device__ __forceinline__ float bfhi(unsigned int u) {
    return __builtin_bit_cast(float, u & 0xFFFF0000u);
}

// ---------------- weight prep: W[k][n] f32 -> Wt[n][k] bf16 ----------------
__global__ __launch_bounds__(256)
void k_prep(const float* __restrict__ Wsp, const float* __restrict__ Wvw,
            const float* __restrict__ Wgl, const float* __restrict__ Wpr,
            unsigned short* __restrict__ o)
{
    const float* W = (blockIdx.x == 0) ? Wsp : (blockIdx.x == 1) ? Wvw
                   : (blockIdx.x == 2) ? Wgl : Wpr;
    unsigned short* Wt = o + (size_t)blockIdx.x * 16384;
    for (int c = threadIdx.x; c < 2048; c += 256) {
        int n = c >> 4, kb = (c & 15) * 8;
        unsigned int p[4];
        #pragma unroll
        for (int j = 0; j < 4; ++j)
            p[j] = pack2bf(W[(kb + 2 * j) * D + n], W[(kb + 2 * j + 1) * D + n]);
        *(short8*)(Wt + n * 128 + kb) = *(short8*)p;
    }
}

// ---------------- CSR build ----------------
__global__ __launch_bounds__(256)
void k_count(const int* __restrict__ vi, const int* __restrict__ pi,
             int* __restrict__ cp, int* __restrict__ cv, int nnz)
{
    int i = blockIdx.x * blockDim.x + threadIdx.x;
    int n = gridDim.x * blockDim.x;
    for (int e = i; e < nnz; e += n) {
        atomicAdd(&cp[pi[e]], 1);
        atomicAdd(&cv[vi[e]], 1);
    }
}

__global__ __launch_bounds__(256)
void k_scanA(const int* __restrict__ cp, int* __restrict__ bsum)
{
    __shared__ int l[256];
    int t = threadIdx.x;
    int4 c = ((const int4*)cp)[blockIdx.x * 256 + t];
    l[t] = c.x + c.y + c.z + c.w;
    __syncthreads();
    for (int d = 128; d > 0; d >>= 1) {
        if (t < d) l[t] += l[t + d];
        __syncthreads();
    }
    if (t == 0) bsum[blockIdx.x] = l[0];
}

__global__ __launch_bounds__(256)
void k_scanB(const int* __restrict__ bsum, int* __restrict__ bbase,
             int* __restrict__ cv, int* __restrict__ bv)
{
    __shared__ int l[256];
    int t = threadIdx.x;
    int own = (t < 64) ? bsum[t] : 0;
    l[t] = own;
    __syncthreads();
    for (int d = 1; d < 64; d <<= 1) {
        int u = (t >= d && t < 64) ? l[t - d] : 0;
        __syncthreads();
        if (t < 64) l[t] += u;
        __syncthreads();
    }
    if (t < 64) bbase[t] = l[t] - own;
    __syncthreads();
    int4 c = ((const int4*)cv)[t];
    int s4 = c.x + c.y + c.z + c.w;
    l[t] = s4;
    __syncthreads();
    for (int d = 1; d < 256; d <<= 1) {
        int u = (t >= d) ? l[t - d] : 0;
        __syncthreads();
        l[t] += u;
        __syncthreads();
    }
    int ex = l[t] - s4;
    int4 o; o.x = ex; o.y = ex + c.x; o.z = o.y + c.y; o.w = o.z + c.z;
    ((int4*)bv)[t] = o;
    ((int4*)cv)[t] = o;
}

__global__ __launch_bounds__(256)
void k_scanC(int* __restrict__ cp, int* __restrict__ bp, const int* __restrict__ bbase)
{
    __shared__ int l[256];
    int t = threadIdx.x;
    int i = blockIdx.x * 256 + t;
    int4 c = ((const int4*)cp)[i];
    int s4 = c.x + c.y + c.z + c.w;
    l[t] = s4;
    __syncthreads();
    for (int d = 1; d < 256; d <<= 1) {
        int u = (t >= d) ? l[t - d] : 0;
        __syncthreads();
        l[t] += u;
        __syncthreads();
    }
    int ex = l[t] - s4 + bbase[blockIdx.x];
    int4 o; o.x = ex; o.y = ex + c.x; o.z = o.y + c.y; o.w = o.z + c.z;
    ((int4*)bp)[i] = o;
    ((int4*)cp)[i] = o;
}

// plist[sp]=entry, psp[sp]=point, psv[sp]=view, vlist[sv]=plist-position
__global__ __launch_bounds__(256)
void k_scatter(const int* __restrict__ vi, const int* __restrict__ pi,
               int* __restrict__ curp, int* __restrict__ curv,
               int* __restrict__ plist, int* __restrict__ psp, int* __restrict__ psv,
               int* __restrict__ vlist, int nnz)
{
    int i = blockIdx.x * blockDim.x + threadIdx.x;
    int n = gridDim.x * blockDim.x;
    for (int e = i; e < nnz; e += n) {
        int p = pi[e], v = vi[e];
        int sp = atomicAdd(&curp[p], 1);
        plist[sp] = e; psp[sp] = p; psv[sp] = v;
        int sv = atomicAdd(&curv[v], 1);
        vlist[sv] = sp;
    }
}

// ---------------- point sums + bf16 row copy (plist-ordered) ----------------
__global__ __launch_bounds__(256)
void k_psum(const float* __restrict__ values, const int* __restrict__ plist,
            const int* __restrict__ pbase, const int* __restrict__ pend,
            unsigned int* __restrict__ mbuf, unsigned int* __restrict__ vbuf16)
{
    int lane = threadIdx.x & 63, wv = threadIdx.x >> 6;
    int wave = blockIdx.x * 4 + wv, nw = gridDim.x * 4;
    for (int pt = wave; pt < NP; pt += nw) {
        int s = pbase[pt], e = pend[pt];
        float s0 = 0.f, s1 = 0.f;
        for (int b = s; b < e; b += 64) {
            int n = min(64, e - b);
            int idx = (lane < n) ? plist[b + lane] : 0;
            int j = 0;
            for (; j + 4 <= n; j += 4) {
                int e0 = __builtin_amdgcn_readlane(idx, j);
                int e1 = __builtin_amdgcn_readlane(idx, j + 1);
                int e2 = __builtin_amdgcn_readlane(idx, j + 2);
                int e3 = __builtin_amdgcn_readlane(idx, j + 3);
                float2 a = *(const float2*)(values + (size_t)e0 * D + lane * 2);
                float2 b2 = *(const float2*)(values + (size_t)e1 * D + lane * 2);
                float2 c = *(const float2*)(values + (size_t)e2 * D + lane * 2);
                float2 d = *(const float2*)(values + (size_t)e3 * D + lane * 2);
                s0 += a.x + b2.x + c.x + d.x;
                s1 += a.y + b2.y + c.y + d.y;
                vbuf16[(size_t)(b + j) * 64 + lane]     = pack2bf(a.x, a.y);
                vbuf16[(size_t)(b + j + 1) * 64 + lane] = pack2bf(b2.x, b2.y);
                vbuf16[(size_t)(b + j + 2) * 64 + lane] = pack2bf(c.x, c.y);
                vbuf16[(size_t)(b + j + 3) * 64 + lane] = pack2bf(d.x, d.y);
            }
            for (; j < n; ++j) {
                int ent = __builtin_amdgcn_readlane(idx, j);
                float2 v = *(const float2*)(values + (size_t)ent * D + lane * 2);
                s0 += v.x; s1 += v.y;
                vbuf16[(size_t)(b + j) * 64 + lane] = pack2bf(v.x, v.y);
            }
        }
        float inv = 1.f / fmaxf((float)(e - s), 1.f);
        mbuf[(size_t)pt * 64 + lane] = pack2bf(s0 * inv, s1 * inv);
    }
}

// ---------------- view sums from bf16 rows (vlist = plist positions) ----------------
__global__ __launch_bounds__(256)
void k_vsum(const unsigned int* __restrict__ vbuf16, const int* __restrict__ vlist,
            const int* __restrict__ vbase, const int* __restrict__ vend,
            unsigned int* __restrict__ mbuf, float* __restrict__ gs)
{
    __shared__ float2 red[4][64];
    int lane = threadIdx.x & 63, wv = threadIdx.x >> 6;
    int v = blockIdx.x;
    int s = vbase[v], e = vend[v];
    float s0 = 0.f, s1 = 0.f;
    for (int b = s + wv * 64; b < e; b += 256) {
        int n = min(64, e - b);
        int idx = (lane < n) ? vlist[b + lane] : 0;
        int j = 0;
        for (; j + 4 <= n; j += 4) {
            int r0 = __builtin_amdgcn_readlane(idx, j);
            int r1 = __builtin_amdgcn_readlane(idx, j + 1);
            int r2 = __builtin_amdgcn_readlane(idx, j + 2);
            int r3 = __builtin_amdgcn_readlane(idx, j + 3);
            unsigned int u0 = vbuf16[(size_t)r0 * 64 + lane];
            unsigned int u1 = vbuf16[(size_t)r1 * 64 + lane];
            unsigned int u2 = vbuf16[(size_t)r2 * 64 + lane];
            unsigned int u3 = vbuf16[(size_t)r3 * 64 + lane];
            s0 += bflo(u0) + bflo(u1) + bflo(u2) + bflo(u3);
            s1 += bfhi(u0) + bfhi(u1) + bfhi(u2) + bfhi(u3);
        }
        for (; j < n; ++j) {
            int r = __builtin_amdgcn_readlane(idx, j);
            unsigned int u = vbuf16[(size_t)r * 64 + lane];
            s0 += bflo(u); s1 += bfhi(u);
        }
    }
    red[wv][lane] = make_float2(s0, s1);
    __syncthreads();
    if (wv == 0) {
        float2 a = red[0][lane], b2 = red[1][lane], c = red[2][lane], d2 = red[3][lane];
        float t0 = a.x + b2.x + c.x + d2.x;
        float t1 = a.y + b2.y + c.y + d2.y;
        atomicAdd(&gs[lane * 2], t0);
        atomicAdd(&gs[lane * 2 + 1], t1);
        float inv = 1.f / fmaxf((float)(e - s), 1.f);
        mbuf[(size_t)(NP + v) * 64 + lane] = pack2bf(t0 * inv, t1 * inv);
    }
}

// ---------------- shared MFMA tile machinery ----------------
// LDS layout: bf16 [128 rows][128 k], byte addr = (row*256 + k*2) ^ ((row&7)<<4)

__device__ __forceinline__ void stage_bf16(const unsigned short* __restrict__ g,
                                           unsigned short* lds, int t)
{
    #pragma unroll
    for (int i = 0; i < 8; ++i) {
        int c = i * 256 + t;
        int row = c >> 4, kb = (c & 15) * 16;
        short8 v = *(const short8*)(g + row * 128 + (c & 15) * 8);
        *(short8*)&lds[((row * 256 + kb) ^ ((row & 7) << 4)) >> 1] = v;
    }
}

__device__ __forceinline__ void mfma_tile(const unsigned short* Al, const unsigned short* Bl,
                                          int lane, int w, f32x4 acc[8][2])
{
    int lr = lane & 15, lg = lane >> 4;
    #pragma unroll
    for (int kc = 0; kc < 4; ++kc) {
        int kb = kc * 64 + lg * 16;
        int bn0 = w * 32 + lr, bn1 = bn0 + 16;
        short8 b0 = *(const short8*)&Bl[((bn0 * 256 + kb) ^ ((bn0 & 7) << 4)) >> 1];
        short8 b1 = *(const short8*)&Bl[((bn1 * 256 + kb) ^ ((bn1 & 7) << 4)) >> 1];
        #pragma unroll
        for (int m = 0; m < 8; ++m) {
            int row = m * 16 + lr;
            short8 a = *(const short8*)&Al[((row * 256 + kb) ^ ((row & 7) << 4)) >> 1];
            acc[m][0] = __builtin_amdgcn_mfma_f32_16x16x32_bf16(a, b0, acc[m][0], 0, 0, 0);
            acc[m][1] = __builtin_amdgcn_mfma_f32_16x16x32_bf16(a, b1, acc[m][1], 0, 0, 0);
        }
    }
}

// ---------------- feature GEMM over all mean rows -> bf16 features ----------------
__global__ __launch_bounds__(256)
void k_featgemm(const unsigned int* __restrict__ mbuf, const unsigned short* __restrict__ Wt4,
                const float* __restrict__ bSp, const float* __restrict__ bVw,
                const float* __restrict__ bGl, const float* __restrict__ gs,
                float inv_nnz, unsigned short* __restrict__ fb)
{
    __shared__ unsigned short Al[128 * 128];
    __shared__ unsigned short Bl[128 * 128];
    int t = threadIdx.x;
    int tile = blockIdx.x;   // 0..520
    const unsigned short* Wt; const float* bias; int rowbase; int vrows = 128;
    if (tile < 512)      { Wt = Wt4;             bias = bSp; rowbase = tile * 128; }
    else if (tile < 520) { Wt = Wt4 + 16384;     bias = bVw; rowbase = NP + (tile - 512) * 128; }
    else                 { Wt = Wt4 + 2 * 16384; bias = bGl; rowbase = NP + NV; vrows = 1; }
    stage_bf16(Wt, Bl, t);
    if (tile < 520) {
        stage_bf16((const unsigned short*)(mbuf + (size_t)rowbase * 64), Al, t);
    } else {
        #pragma unroll
        for (int i = 0; i < 8; ++i) {
            int c = i * 256 + t;
            int row = c >> 4, cb = (c & 15) * 8;
            unsigned int p[4] = {0u, 0u, 0u, 0u};
            if (row == 0) {
                #pragma unroll
                for (int j = 0; j < 4; ++j)
                    p[j] = pack2bf(gs[cb + 2 * j] * inv_nnz, gs[cb + 2 * j + 1] * inv_nnz);
            }
            *(short8*)&Al[((row * 256 + cb * 2) ^ ((row & 7) << 4)) >> 1] = *(short8*)p;
        }
    }
    __syncthreads();
    f32x4 acc[8][2] = {};
    int lane = t & 63, w = t >> 6;
    mfma_tile(Al, Bl, lane, w, acc);
    int lr = lane & 15, lg = lane >> 4;
    int c0 = w * 32 + lr, c1 = c0 + 16;
    float bb0 = 0.25f * bias[c0], bb1 = 0.25f * bias[c1];
    #pragma unroll
    for (int m = 0; m < 8; ++m)
        #pragma unroll
        for (int r = 0; r < 4; ++r) {
            int row = m * 16 + lg * 4 + r;
            if (row < vrows) {
                fb[(size_t)(rowbase + row) * D + c0] = f2bf(acc[m][0][r] * 0.25f + bb0);
                fb[(size_t)(rowbase + row) * D + c1] = f2bf(acc[m][1][r] * 0.25f + bb1);
            }
        }
}

// ---------------- projection (plist order): sequential A, scattered out rows ----------------
__global__ __launch_bounds__(256, 4)
void k_proj(const unsigned int* __restrict__ vbuf16, const int* __restrict__ plist,
            const int* __restrict__ psp, const int* __restrict__ psv,
            const unsigned short* __restrict__ WtPr, const float* __restrict__ bPr,
            const unsigned short* __restrict__ fb, float* __restrict__ out,
            int nnz, int ntiles)
{
    __shared__ unsigned short Al[128 * 128];   // 32 KB
    __shared__ int eI[128], pI[128], vI[128];
    int t = threadIdx.x, lane = t & 63, w = t >> 6;
    int lr = lane & 15, lg = lane >> 4;
    short8 Bf[4][2];
    #pragma unroll
    for (int kc = 0; kc < 4; ++kc) {
        Bf[kc][0] = *(const short8*)(WtPr + (w * 32 + lr) * 128 + kc * 32 + lg * 8);
        Bf[kc][1] = *(const short8*)(WtPr + (w * 32 + lr + 16) * 128 + kc * 32 + lg * 8);
    }
    int c0 = w * 32 + lr, c1 = c0 + 16;
    const unsigned short* gfr = fb + (size_t)(NP + NV) * D;
    float base0 = 0.25f * bPr[c0] + bf2f(gfr[c0]);
    float base1 = 0.25f * bPr[c1] + bf2f(gfr[c1]);
    const unsigned short* pfb = fb;
    const unsigned short* vfb = fb + (size_t)NP * D;
    for (int tile = blockIdx.x; tile < ntiles; tile += gridDim.x) {
        int s = tile * 128;
        int vrows = min(128, nnz - s);
        stage_bf16((const unsigned short*)(vbuf16 + (size_t)s * 64), Al, t);
        if (t < 128) {
            int ok = t < vrows;
            eI[t] = ok ? plist[s + t] : 0;
            pI[t] = ok ? psp[s + t] : 0;
            vI[t] = ok ? psv[s + t] : 0;
        }
        __syncthreads();
        f32x4 acc[8][2] = {};
        #pragma unroll
        for (int kc = 0; kc < 4; ++kc) {
            int kb = kc * 64 + lg * 16;
            #pragma unroll
            for (int m = 0; m < 8; ++m) {
                int row = m * 16 + lr;
                short8 a = *(const short8*)&Al[((row * 256 + kb) ^ ((row & 7) << 4)) >> 1];
                acc[m][0] = __builtin_amdgcn_mfma_f32_16x16x32_bf16(a, Bf[kc][0], acc[m][0], 0, 0, 0);
                acc[m][1] = __builtin_amdgcn_mfma_f32_16x16x32_bf16(a, Bf[kc][1], acc[m][1], 0, 0, 0);
            }
        }
        #pragma unroll
        for (int m = 0; m < 8; ++m)
            #pragma unroll
            for (int r = 0; r < 4; ++r) {
                int row = m * 16 + lg * 4 + r;
                if (row < vrows) {
                    int e = eI[row], p = pI[row], vv = vI[row];
                    float pf0 = bf2f(pfb[(size_t)p * D + c0]);
                    float pf1 = bf2f(pfb[(size_t)p * D + c1]);
                    float vf0 = bf2f(vfb[(size_t)vv * D + c0]);
                    float vf1 = bf2f(vfb[(size_t)vv * D + c1]);
                    size_t o = (size_t)e * D;
                    out[o + c0] = acc[m][0][r] * 0.25f + base0 + pf0 + vf0;
                    out[o + c1] = acc[m][1][r] * 0.25f + base1 + pf1 + vf1;
                }
            }
        __syncthreads();
    }
}

extern "C" void kernel_launch(void* const* d_in, const int* in_sizes, int n_in,
                              void* d_out, int out_size, void* d_ws, size_t ws_size,
                              hipStream_t stream)
{
    const float* values    = (const float*)d_in[0];
    const int*   view_idx  = (const int*)d_in[1];
    const int*   point_idx = (const int*)d_in[2];
    const float* W_sp   = (const float*)d_in[5];
    const float* b_sp   = (const float*)d_in[6];
    const float* W_view = (const float*)d_in[7];
    const float* b_view = (const float*)d_in[8];
    const float* W_glob = (const float*)d_in[9];
    const float* b_glob = (const float*)d_in[10];
    const float* W_proj = (const float*)d_in[11];
    const float* b_proj = (const float*)d_in[12];
    int nnz = in_sizes[1];
    int ntiles = (nnz + 127) / 128;

    // ws: [gs|Cp|Cv](memset) | bsum|bbase|Bp|Bv | plist|psp|psv|vlist | Wt4 | mbuf | fb16 | vbuf16
    char* w = (char*)d_ws;
    float* gs = (float*)w;                          w += 128 * 4;
    int* Cp   = (int*)w;                            w += (size_t)NP * 4;
    int* Cv   = (int*)w;                            w += (size_t)NV * 4;
    size_t zero_bytes = (size_t)(w - (char*)d_ws);
    int* bsum = (int*)w;                            w += 64 * 4;
    int* bbase = (int*)w;                           w += 64 * 4;
    int* Bp   = (int*)w;                            w += (size_t)NP * 4;
    int* Bv   = (int*)w;                            w += (size_t)NV * 4;
    int* plist = (int*)w;                           w += (size_t)nnz * 4;
    int* psp  = (int*)w;                            w += (size_t)nnz * 4;
    int* psv  = (int*)w;                            w += (size_t)nnz * 4;
    int* vlist = (int*)w;                           w += (size_t)nnz * 4;
    unsigned short* Wt4 = (unsigned short*)w;       w += (size_t)4 * 16384 * 2;
    unsigned int* mbuf = (unsigned int*)w;          w += (size_t)(NP + NV) * 64 * 4;
    unsigned short* fb16 = (unsigned short*)w;      w += (size_t)(NP + NV + 1) * D * 2;
    unsigned int* vbuf16 = (unsigned int*)w;        w += (size_t)ntiles * 128 * 64 * 4;

    hipMemsetAsync(d_ws, 0, zero_bytes, stream);

    hipLaunchKernelGGL(k_prep, dim3(4), dim3(256), 0, stream,
                       W_sp, W_view, W_glob, W_proj, Wt4);
    hipLaunchKernelGGL(k_count, dim3(1024), dim3(256), 0, stream,
                       view_idx, point_idx, Cp, Cv, nnz);
    hipLaunchKernelGGL(k_scanA, dim3(64), dim3(256), 0, stream, Cp, bsum);
    hipLaunchKernelGGL(k_scanB, dim3(1), dim3(256), 0, stream, bsum, bbase, Cv, Bv);
    hipLaunchKernelGGL(k_scanC, dim3(64), dim3(256), 0, stream, Cp, Bp, bbase);
    hipLaunchKernelGGL(k_scatter, dim3(1024), dim3(256), 0, stream,
                       view_idx, point_idx, Cp, Cv, plist, psp, psv, vlist, nnz);
    hipLaunchKernelGGL(k_psum, dim3(2048), dim3(256), 0, stream,
                       values, plist, Bp, Cp, mbuf, vbuf16);
    hipLaunchKernelGGL(k_vsum, dim3(NV), dim3(256), 0, stream,
                       vbuf16, vlist, Bv, Cv, mbuf, gs);
    hipLaunchKernelGGL(k_featgemm, dim3(521), dim3(256), 0, stream,
                       mbuf, Wt4, b_sp, b_view, b_glob, gs, 1.f / (float)nnz, fb16);
    hipLaunchKernelGGL(k_proj, dim3(2048), dim3(256), 0, stream,
                       vbuf16, plist, psp, psv, Wt4 + (size_t)3 * 16384, b_proj, fb16,
                       (float*)d_out, nnz, ntiles);
}

// Round 6
// 1060.029 us; speedup vs baseline: 2.0339x; 1.0725x over previous
//
#include <hip/hip_runtime.h>

#define D 128
#define NP 65536
#define NV 1024

typedef __attribute__((ext_vector_type(8))) short short8;
typedef __attribute__((ext_vector_type(4))) float f32x4;

__device__ __forceinline__ unsigned short f2bf(float x) {
    unsigned int u = __builtin_bit_cast(unsigned int, x);
    u += 0x7FFFu + ((u >> 16) & 1u);          // round-to-nearest-even
    return (unsigned short)(u >> 16);
}
__device__ __forceinline__ unsigned int pack2bf(float a, float b) {
    return (unsigned int)f2bf(a) | ((unsigned int)f2bf(b) << 16);
}
__device__ __forceinline__ float bflo(unsigned int u) {
    return __builtin_bit_cast(float, u << 16);
}
__device__ __forceinline__ float bfhi(unsigned int u) {
    return __builtin_bit_cast(float, u & 0xFFFF0000u);
}

// ---------------- weight prep: W[k][n] f32 -> Wt[n][k] bf16 ----------------
__global__ __launch_bounds__(256)
void k_prep(const float* __restrict__ Wsp, const float* __restrict__ Wvw,
            const float* __restrict__ Wgl, const float* __restrict__ Wpr,
            unsigned short* __restrict__ o)
{
    const float* W = (blockIdx.x == 0) ? Wsp : (blockIdx.x == 1) ? Wvw
                   : (blockIdx.x == 2) ? Wgl : Wpr;
    unsigned short* Wt = o + (size_t)blockIdx.x * 16384;
    for (int c = threadIdx.x; c < 2048; c += 256) {
        int n = c >> 4, kb = (c & 15) * 8;
        unsigned int p[4];
        #pragma unroll
        for (int j = 0; j < 4; ++j)
            p[j] = pack2bf(W[(kb + 2 * j) * D + n], W[(kb + 2 * j + 1) * D + n]);
        *(short8*)(Wt + n * 128 + kb) = *(short8*)p;
    }
}

// ---------------- CSR build ----------------
__global__ __launch_bounds__(256)
void k_count(const int* __restrict__ vi, const int* __restrict__ pi,
             int* __restrict__ cp, int* __restrict__ cv, int nnz)
{
    int i = blockIdx.x * blockDim.x + threadIdx.x;
    int n = gridDim.x * blockDim.x;
    for (int e = i; e < nnz; e += n) {
        atomicAdd(&cp[pi[e]], 1);
        atomicAdd(&cv[vi[e]], 1);
    }
}

__global__ __launch_bounds__(256)
void k_scanA(const int* __restrict__ cp, int* __restrict__ bsum)
{
    __shared__ int l[256];
    int t = threadIdx.x;
    int4 c = ((const int4*)cp)[blockIdx.x * 256 + t];
    l[t] = c.x + c.y + c.z + c.w;
    __syncthreads();
    for (int d = 128; d > 0; d >>= 1) {
        if (t < d) l[t] += l[t + d];
        __syncthreads();
    }
    if (t == 0) bsum[blockIdx.x] = l[0];
}

__global__ __launch_bounds__(256)
void k_scanB(const int* __restrict__ bsum, int* __restrict__ bbase,
             int* __restrict__ cv, int* __restrict__ bv)
{
    __shared__ int l[256];
    int t = threadIdx.x;
    int own = (t < 64) ? bsum[t] : 0;
    l[t] = own;
    __syncthreads();
    for (int d = 1; d < 64; d <<= 1) {
        int u = (t >= d && t < 64) ? l[t - d] : 0;
        __syncthreads();
        if (t < 64) l[t] += u;
        __syncthreads();
    }
    if (t < 64) bbase[t] = l[t] - own;
    __syncthreads();
    int4 c = ((const int4*)cv)[t];
    int s4 = c.x + c.y + c.z + c.w;
    l[t] = s4;
    __syncthreads();
    for (int d = 1; d < 256; d <<= 1) {
        int u = (t >= d) ? l[t - d] : 0;
        __syncthreads();
        l[t] += u;
        __syncthreads();
    }
    int ex = l[t] - s4;
    int4 o; o.x = ex; o.y = ex + c.x; o.z = o.y + c.y; o.w = o.z + c.z;
    ((int4*)bv)[t] = o;
    ((int4*)cv)[t] = o;
}

__global__ __launch_bounds__(256)
void k_scanC(int* __restrict__ cp, int* __restrict__ bp, const int* __restrict__ bbase)
{
    __shared__ int l[256];
    int t = threadIdx.x;
    int i = blockIdx.x * 256 + t;
    int4 c = ((const int4*)cp)[i];
    int s4 = c.x + c.y + c.z + c.w;
    l[t] = s4;
    __syncthreads();
    for (int d = 1; d < 256; d <<= 1) {
        int u = (t >= d) ? l[t - d] : 0;
        __syncthreads();
        l[t] += u;
        __syncthreads();
    }
    int ex = l[t] - s4 + bbase[blockIdx.x];
    int4 o; o.x = ex; o.y = ex + c.x; o.z = o.y + c.y; o.w = o.z + c.z;
    ((int4*)bp)[i] = o;
    ((int4*)cp)[i] = o;
}

// ---------------- scatter + bf16 convert (sequential values read) ----------------
// plv[sp] = (entry, view); vlist[sv] = sp; vbuf16[sp] = bf16 row of entry.
__global__ __launch_bounds__(256)
void k_scatter_cvt(const float* __restrict__ values, const int* __restrict__ vi,
                   const int* __restrict__ pi, int* __restrict__ curp,
                   int* __restrict__ curv, uint2* __restrict__ plv,
                   int* __restrict__ vlist, unsigned int* __restrict__ vbuf16, int nnz)
{
    int lane = threadIdx.x & 63, wv = threadIdx.x >> 6;
    int wave = blockIdx.x * 4 + wv, nw = gridDim.x * 4;
    for (int base = wave * 64; base < nnz; base += nw * 64) {
        int e = base + lane;
        int sp = 0;
        if (e < nnz) {
            int p = pi[e], v = vi[e];
            sp = atomicAdd(&curp[p], 1);
            int sv = atomicAdd(&curv[v], 1);
            plv[sp] = make_uint2((unsigned)e, (unsigned)v);
            vlist[sv] = sp;
        }
        int n = min(64, nnz - base);
        int j = 0;
        for (; j + 4 <= n; j += 4) {
            int s0 = __builtin_amdgcn_readlane(sp, j);
            int s1 = __builtin_amdgcn_readlane(sp, j + 1);
            int s2 = __builtin_amdgcn_readlane(sp, j + 2);
            int s3 = __builtin_amdgcn_readlane(sp, j + 3);
            float2 a = *(const float2*)(values + (size_t)(base + j) * D + lane * 2);
            float2 b = *(const float2*)(values + (size_t)(base + j + 1) * D + lane * 2);
            float2 c = *(const float2*)(values + (size_t)(base + j + 2) * D + lane * 2);
            float2 d = *(const float2*)(values + (size_t)(base + j + 3) * D + lane * 2);
            vbuf16[(size_t)s0 * 64 + lane] = pack2bf(a.x, a.y);
            vbuf16[(size_t)s1 * 64 + lane] = pack2bf(b.x, b.y);
            vbuf16[(size_t)s2 * 64 + lane] = pack2bf(c.x, c.y);
            vbuf16[(size_t)s3 * 64 + lane] = pack2bf(d.x, d.y);
        }
        for (; j < n; ++j) {
            int s0 = __builtin_amdgcn_readlane(sp, j);
            float2 a = *(const float2*)(values + (size_t)(base + j) * D + lane * 2);
            vbuf16[(size_t)s0 * 64 + lane] = pack2bf(a.x, a.y);
        }
    }
}

// ---------------- point sums: fully sequential over vbuf16 ----------------
__global__ __launch_bounds__(256)
void k_psum(const unsigned int* __restrict__ vbuf16, const int* __restrict__ pbase,
            const int* __restrict__ pend, unsigned int* __restrict__ mbuf,
            int* __restrict__ psp)
{
    int lane = threadIdx.x & 63, wv = threadIdx.x >> 6;
    int wave = blockIdx.x * 4 + wv, nw = gridDim.x * 4;
    for (int pt = wave; pt < NP; pt += nw) {
        int s = pbase[pt], e = pend[pt];
        float s0 = 0.f, s1 = 0.f;
        int i = s;
        for (; i + 4 <= e; i += 4) {
            unsigned int u0 = vbuf16[(size_t)i * 64 + lane];
            unsigned int u1 = vbuf16[(size_t)(i + 1) * 64 + lane];
            unsigned int u2 = vbuf16[(size_t)(i + 2) * 64 + lane];
            unsigned int u3 = vbuf16[(size_t)(i + 3) * 64 + lane];
            s0 += bflo(u0) + bflo(u1) + bflo(u2) + bflo(u3);
            s1 += bfhi(u0) + bfhi(u1) + bfhi(u2) + bfhi(u3);
        }
        for (; i < e; ++i) {
            unsigned int u = vbuf16[(size_t)i * 64 + lane];
            s0 += bflo(u); s1 += bfhi(u);
        }
        for (int q = s + lane; q < e; q += 64) psp[q] = pt;
        float inv = 1.f / fmaxf((float)(e - s), 1.f);
        mbuf[(size_t)pt * 64 + lane] = pack2bf(s0 * inv, s1 * inv);
    }
}

// ---------------- view sums from bf16 rows (vlist = plist positions) ----------------
__global__ __launch_bounds__(256)
void k_vsum(const unsigned int* __restrict__ vbuf16, const int* __restrict__ vlist,
            const int* __restrict__ vbase, const int* __restrict__ vend,
            unsigned int* __restrict__ mbuf, float* __restrict__ gs)
{
    __shared__ float2 red[4][64];
    int lane = threadIdx.x & 63, wv = threadIdx.x >> 6;
    int v = blockIdx.x;
    int s = vbase[v], e = vend[v];
    float s0 = 0.f, s1 = 0.f;
    for (int b = s + wv * 64; b < e; b += 256) {
        int n = min(64, e - b);
        int idx = (lane < n) ? vlist[b + lane] : 0;
        int j = 0;
        for (; j + 4 <= n; j += 4) {
            int r0 = __builtin_amdgcn_readlane(idx, j);
            int r1 = __builtin_amdgcn_readlane(idx, j + 1);
            int r2 = __builtin_amdgcn_readlane(idx, j + 2);
            int r3 = __builtin_amdgcn_readlane(idx, j + 3);
            unsigned int u0 = vbuf16[(size_t)r0 * 64 + lane];
            unsigned int u1 = vbuf16[(size_t)r1 * 64 + lane];
            unsigned int u2 = vbuf16[(size_t)r2 * 64 + lane];
            unsigned int u3 = vbuf16[(size_t)r3 * 64 + lane];
            s0 += bflo(u0) + bflo(u1) + bflo(u2) + bflo(u3);
            s1 += bfhi(u0) + bfhi(u1) + bfhi(u2) + bfhi(u3);
        }
        for (; j < n; ++j) {
            int r = __builtin_amdgcn_readlane(idx, j);
            unsigned int u = vbuf16[(size_t)r * 64 + lane];
            s0 += bflo(u); s1 += bfhi(u);
        }
    }
    red[wv][lane] = make_float2(s0, s1);
    __syncthreads();
    if (wv == 0) {
        float2 a = red[0][lane], b2 = red[1][lane], c = red[2][lane], d2 = red[3][lane];
        float t0 = a.x + b2.x + c.x + d2.x;
        float t1 = a.y + b2.y + c.y + d2.y;
        atomicAdd(&gs[lane * 2], t0);
        atomicAdd(&gs[lane * 2 + 1], t1);
        float inv = 1.f / fmaxf((float)(e - s), 1.f);
        mbuf[(size_t)(NP + v) * 64 + lane] = pack2bf(t0 * inv, t1 * inv);
    }
}

// ---------------- shared MFMA tile machinery ----------------
// LDS layout: bf16 [128 rows][128 k], byte addr = (row*256 + k*2) ^ ((row&7)<<4)

__device__ __forceinline__ void stage_bf16(const unsigned short* __restrict__ g,
                                           unsigned short* lds, int t)
{
    #pragma unroll
    for (int i = 0; i < 8; ++i) {
        int c = i * 256 + t;
        int row = c >> 4, kb = (c & 15) * 16;
        short8 v = *(const short8*)(g + row * 128 + (c & 15) * 8);
        *(short8*)&lds[((row * 256 + kb) ^ ((row & 7) << 4)) >> 1] = v;
    }
}

__device__ __forceinline__ void mfma_tile(const unsigned short* Al, const unsigned short* Bl,
                                          int lane, int w, f32x4 acc[8][2])
{
    int lr = lane & 15, lg = lane >> 4;
    #pragma unroll
    for (int kc = 0; kc < 4; ++kc) {
        int kb = kc * 64 + lg * 16;
        int bn0 = w * 32 + lr, bn1 = bn0 + 16;
        short8 b0 = *(const short8*)&Bl[((bn0 * 256 + kb) ^ ((bn0 & 7) << 4)) >> 1];
        short8 b1 = *(const short8*)&Bl[((bn1 * 256 + kb) ^ ((bn1 & 7) << 4)) >> 1];
        #pragma unroll
        for (int m = 0; m < 8; ++m) {
            int row = m * 16 + lr;
            short8 a = *(const short8*)&Al[((row * 256 + kb) ^ ((row & 7) << 4)) >> 1];
            acc[m][0] = __builtin_amdgcn_mfma_f32_16x16x32_bf16(a, b0, acc[m][0], 0, 0, 0);
            acc[m][1] = __builtin_amdgcn_mfma_f32_16x16x32_bf16(a, b1, acc[m][1], 0, 0, 0);
        }
    }
}

// ---------------- feature GEMM -> packed (c,c+16) uint rows ----------------
__global__ __launch_bounds__(256)
void k_featgemm(const unsigned int* __restrict__ mbuf, const unsigned short* __restrict__ Wt4,
                const float* __restrict__ bSp, const float* __restrict__ bVw,
                const float* __restrict__ bGl, const float* __restrict__ gs,
                float inv_nnz, unsigned int* __restrict__ fbp)
{
    __shared__ unsigned short Al[128 * 128];
    __shared__ unsigned short Bl[128 * 128];
    int t = threadIdx.x;
    int tile = blockIdx.x;   // 0..520
    const unsigned short* Wt; const float* bias; int rowbase; int vrows = 128;
    if (tile < 512)      { Wt = Wt4;             bias = bSp; rowbase = tile * 128; }
    else if (tile < 520) { Wt = Wt4 + 16384;     bias = bVw; rowbase = NP + (tile - 512) * 128; }
    else                 { Wt = Wt4 + 2 * 16384; bias = bGl; rowbase = NP + NV; vrows = 1; }
    stage_bf16(Wt, Bl, t);
    if (tile < 520) {
        stage_bf16((const unsigned short*)(mbuf + (size_t)rowbase * 64), Al, t);
    } else {
        #pragma unroll
        for (int i = 0; i < 8; ++i) {
            int c = i * 256 + t;
            int row = c >> 4, cb = (c & 15) * 8;
            unsigned int p[4] = {0u, 0u, 0u, 0u};
            if (row == 0) {
                #pragma unroll
                for (int j = 0; j < 4; ++j)
                    p[j] = pack2bf(gs[cb + 2 * j] * inv_nnz, gs[cb + 2 * j + 1] * inv_nnz);
            }
            *(short8*)&Al[((row * 256 + cb * 2) ^ ((row & 7) << 4)) >> 1] = *(short8*)p;
        }
    }
    __syncthreads();
    f32x4 acc[8][2] = {};
    int lane = t & 63, w = t >> 6;
    mfma_tile(Al, Bl, lane, w, acc);
    int lr = lane & 15, lg = lane >> 4;
    int c0 = w * 32 + lr, c1 = c0 + 16;
    float bb0 = 0.25f * bias[c0], bb1 = 0.25f * bias[c1];
    #pragma unroll
    for (int m = 0; m < 8; ++m)
        #pragma unroll
        for (int r = 0; r < 4; ++r) {
            int row = m * 16 + lg * 4 + r;
            if (row < vrows)
                fbp[(size_t)(rowbase + row) * 64 + w * 16 + lr] =
                    pack2bf(acc[m][0][r] * 0.25f + bb0, acc[m][1][r] * 0.25f + bb1);
        }
}

// ---------------- projection (plist order) ----------------
__global__ __launch_bounds__(256, 4)
void k_proj(const unsigned int* __restrict__ vbuf16, const uint2* __restrict__ plv,
            const int* __restrict__ psp, const unsigned short* __restrict__ WtPr,
            const float* __restrict__ bPr, const unsigned int* __restrict__ fbp,
            float* __restrict__ out, int nnz, int ntiles)
{
    __shared__ unsigned short Al[128 * 128];   // 32 KB
    __shared__ int eI[128], pI[128], vI[128];
    int t = threadIdx.x, lane = t & 63, w = t >> 6;
    int lr = lane & 15, lg = lane >> 4;
    short8 Bf[4][2];
    #pragma unroll
    for (int kc = 0; kc < 4; ++kc) {
        Bf[kc][0] = *(const short8*)(WtPr + (w * 32 + lr) * 128 + kc * 32 + lg * 8);
        Bf[kc][1] = *(const short8*)(WtPr + (w * 32 + lr + 16) * 128 + kc * 32 + lg * 8);
    }
    int c0 = w * 32 + lr, c1 = c0 + 16;
    unsigned int gw = fbp[(size_t)(NP + NV) * 64 + w * 16 + lr];
    float base0 = 0.25f * bPr[c0] + bflo(gw);
    float base1 = 0.25f * bPr[c1] + bfhi(gw);
    const unsigned int* pfp = fbp;
    const unsigned int* vfp = fbp + (size_t)NP * 64;
    for (int tile = blockIdx.x; tile < ntiles; tile += gridDim.x) {
        int s = tile * 128;
        int vrows = min(128, nnz - s);
        stage_bf16((const unsigned short*)(vbuf16 + (size_t)s * 64), Al, t);
        if (t < 128) {
            int ok = t < vrows;
            uint2 q = ok ? plv[s + t] : make_uint2(0u, 0u);
            eI[t] = (int)q.x;
            vI[t] = (int)q.y;
            pI[t] = ok ? psp[s + t] : 0;
        }
        __syncthreads();
        f32x4 acc[8][2] = {};
        #pragma unroll
        for (int kc = 0; kc < 4; ++kc) {
            int kb = kc * 64 + lg * 16;
            #pragma unroll
            for (int m = 0; m < 8; ++m) {
                int row = m * 16 + lr;
                short8 a = *(const short8*)&Al[((row * 256 + kb) ^ ((row & 7) << 4)) >> 1];
                acc[m][0] = __builtin_amdgcn_mfma_f32_16x16x32_bf16(a, Bf[kc][0], acc[m][0], 0, 0, 0);
                acc[m][1] = __builtin_amdgcn_mfma_f32_16x16x32_bf16(a, Bf[kc][1], acc[m][1], 0, 0, 0);
            }
        }
        #pragma unroll
        for (int m = 0; m < 8; ++m)
            #pragma unroll
            for (int r = 0; r < 4; ++r) {
                int row = m * 16 + lg * 4 + r;
                if (row < vrows) {
                    int e = eI[row], p = pI[row], vv = vI[row];
                    unsigned int pu = pfp[(size_t)p * 64 + w * 16 + lr];
                    unsigned int vu = vfp[(size_t)vv * 64 + w * 16 + lr];
                    size_t o = (size_t)e * D;
                    out[o + c0] = acc[m][0][r] * 0.25f + base0 + bflo(pu) + bflo(vu);
                    out[o + c1] = acc[m][1][r] * 0.25f + base1 + bfhi(pu) + bfhi(vu);
                }
            }
        __syncthreads();
    }
}

extern "C" void kernel_launch(void* const* d_in, const int* in_sizes, int n_in,
                              void* d_out, int out_size, void* d_ws, size_t ws_size,
                              hipStream_t stream)
{
    const float* values    = (const float*)d_in[0];
    const int*   view_idx  = (const int*)d_in[1];
    const int*   point_idx = (const int*)d_in[2];
    const float* W_sp   = (const float*)d_in[5];
    const float* b_sp   = (const float*)d_in[6];
    const float* W_view = (const float*)d_in[7];
    const float* b_view = (const float*)d_in[8];
    const float* W_glob = (const float*)d_in[9];
    const float* b_glob = (const float*)d_in[10];
    const float* W_proj = (const float*)d_in[11];
    const float* b_proj = (const float*)d_in[12];
    int nnz = in_sizes[1];
    int ntiles = (nnz + 127) / 128;

    // ws: [gs|Cp|Cv](memset) | bsum|bbase|Bp|Bv | plv|vlist|psp | Wt4 | mbuf | fbp | vbuf16
    char* w = (char*)d_ws;
    float* gs = (float*)w;                          w += 128 * 4;
    int* Cp   = (int*)w;                            w += (size_t)NP * 4;
    int* Cv   = (int*)w;                            w += (size_t)NV * 4;
    size_t zero_bytes = (size_t)(w - (char*)d_ws);
    int* bsum = (int*)w;                            w += 64 * 4;
    int* bbase = (int*)w;                           w += 64 * 4;
    int* Bp   = (int*)w;                            w += (size_t)NP * 4;
    int* Bv   = (int*)w;                            w += (size_t)NV * 4;
    uint2* plv = (uint2*)w;                         w += (size_t)nnz * 8;
    int* vlist = (int*)w;                           w += (size_t)nnz * 4;
    int* psp  = (int*)w;                            w += (size_t)nnz * 4;
    unsigned short* Wt4 = (unsigned short*)w;       w += (size_t)4 * 16384 * 2;
    unsigned int* mbuf = (unsigned int*)w;          w += (size_t)(NP + NV) * 64 * 4;
    unsigned int* fbp = (unsigned int*)w;           w += (size_t)(NP + NV + 1) * 64 * 4;
    unsigned int* vbuf16 = (unsigned int*)w;        w += (size_t)ntiles * 128 * 64 * 4;

    hipMemsetAsync(d_ws, 0, zero_bytes, stream);

    hipLaunchKernelGGL(k_prep, dim3(4), dim3(256), 0, stream,
                       W_sp, W_view, W_glob, W_proj, Wt4);
    hipLaunchKernelGGL(k_count, dim3(1024), dim3(256), 0, stream,
                       view_idx, point_idx, Cp, Cv, nnz);
    hipLaunchKernelGGL(k_scanA, dim3(64), dim3(256), 0, stream, Cp, bsum);
    hipLaunchKernelGGL(k_scanB, dim3(1), dim3(256), 0, stream, bsum, bbase, Cv, Bv);
    hipLaunchKernelGGL(k_scanC, dim3(64), dim3(256), 0, stream, Cp, Bp, bbase);
    hipLaunchKernelGGL(k_scatter_cvt, dim3(2048), dim3(256), 0, stream,
                       values, view_idx, point_idx, Cp, Cv, plv, vlist, vbuf16, nnz);
    hipLaunchKernelGGL(k_psum, dim3(2048), dim3(256), 0, stream,
                       vbuf16, Bp, Cp, mbuf, psp);
    hipLaunchKernelGGL(k_vsum, dim3(NV), dim3(256), 0, stream,
                       vbuf16, vlist, Bv, Cv, mbuf, gs);
    hipLaunchKernelGGL(k_featgemm, dim3(521), dim3(256), 0, stream,
                       mbuf, Wt4, b_sp, b_view, b_glob, gs, 1.f / (float)nnz, fbp);
    hipLaunchKernelGGL(k_proj, dim3(2048), dim3(256), 0, stream,
                       vbuf16, plv, psp, Wt4 + (size_t)3 * 16384, b_proj, fbp,
                       (float*)d_out, nnz, ntiles);
}